// Round 10
// baseline (343.180 us; speedup 1.0000x reference)
//
#include <hip/hip_runtime.h>
#include <hip/hip_bf16.h>

#define M_TOK 2048
#define K_DIM 1024
#define E_NUM 8
#define DFF   2816
#define TOPK  2
#define NROWS (M_TOK*TOPK)   // 4096 routed rows
#define KSPLIT 2
#define KT2    (DFF / 64 / KSPLIT)   // 22

typedef __bf16 bf16;
typedef __bf16 bf16x8 __attribute__((ext_vector_type(8)));
typedef __bf16 bf16x4 __attribute__((ext_vector_type(4)));
typedef float  f32x4  __attribute__((ext_vector_type(4)));

__device__ __forceinline__ void gload_lds16(const bf16* g, bf16* l) {
    __builtin_amdgcn_global_load_lds(
        (const __attribute__((address_space(1))) void*)g,
        (__attribute__((address_space(3))) void*)l, 16, 0, 0);
}

// ---------------------------------------------------------------------------
// Zero d_out (grid-stride f32x4).
// ---------------------------------------------------------------------------
__global__ __launch_bounds__(256)
void zero_kernel(float* __restrict__ p, int n4)
{
    int i = blockIdx.x * 256 + threadIdx.x;
    int stride = gridDim.x * 256;
    f32x4 z = (f32x4){0.f, 0.f, 0.f, 0.f};
    for (; i < n4; i += stride) ((f32x4*)p)[i] = z;
}

// ---------------------------------------------------------------------------
// Routing (unchanged, verified).
// ---------------------------------------------------------------------------
__global__ __launch_bounds__(512)
void route_kernel(const int* __restrict__ ids,
                  const float* __restrict__ tw,
                  int* __restrict__ counts, int* __restrict__ offs,
                  int* __restrict__ row_token, float* __restrict__ row_wgt)
{
    const int e    = threadIdx.x >> 6;
    const int lane = threadIdx.x & 63;
    __shared__ int scnt[E_NUM];

    int cnt = 0;
    for (int i0 = 0; i0 < NROWS; i0 += 64) {
        int id = ids[i0 + lane];
        cnt += __popcll(__ballot(id == e));
    }
    if (lane == 0) scnt[e] = cnt;
    __syncthreads();
    int base = 0;
    for (int j = 0; j < e; ++j) base += scnt[j];
    if (lane == 0) { counts[e] = cnt; offs[e] = base; }

    const unsigned long long ltmask = (1ull << lane) - 1ull;
    int pos = base;
    for (int i0 = 0; i0 < NROWS; i0 += 64) {
        int i = i0 + lane;
        int id = ids[i];
        unsigned long long m = __ballot(id == e);
        if (id == e) {
            int rank = __popcll(m & ltmask);
            row_token[pos + rank] = i >> 1;
            row_wgt[pos + rank]   = tw[i];
        }
        pos += __popcll(m);
    }
}

// ---------------------------------------------------------------------------
// fp32 -> bf16 cast for BOTH weight tensors in one launch (ranges chained).
// ---------------------------------------------------------------------------
__global__ __launch_bounds__(256)
void cast2_kernel(const float* __restrict__ s1, bf16* __restrict__ d1, long n1_8,
                  const float* __restrict__ s2, bf16* __restrict__ d2, long n2_8)
{
    long i = (long)blockIdx.x * 256 + threadIdx.x;
    long stride = (long)gridDim.x * 256;
    long ntot = n1_8 + n2_8;
    for (; i < ntot; i += stride) {
        const float* s; bf16* d; long j;
        if (i < n1_8) { s = s1; d = d1; j = i; }
        else          { s = s2; d = d2; j = i - n1_8; }
        f32x4 a = ((const f32x4*)s)[2*j];
        f32x4 b = ((const f32x4*)s)[2*j + 1];
        bf16x8 v;
        #pragma unroll
        for (int k = 0; k < 4; ++k) { v[k] = (bf16)a[k]; v[k+4] = (bf16)b[k]; }
        ((bf16x8*)d)[j] = v;
    }
}

// ---------------------------------------------------------------------------
// Gather routed rows of X and cast to bf16.
// ---------------------------------------------------------------------------
__global__ __launch_bounds__(256)
void gather_cast_kernel(const float* __restrict__ X, const int* __restrict__ row_token,
                        bf16* __restrict__ Ag)
{
    const int row = blockIdx.x;
    const int tok = row_token[row];
    f32x4 a = ((const f32x4*)(X + (size_t)tok * K_DIM))[threadIdx.x];
    bf16x4 v;
    #pragma unroll
    for (int j = 0; j < 4; ++j) v[j] = (bf16)a[j];
    ((bf16x4*)(Ag + (size_t)row * K_DIM))[threadIdx.x] = v;
}

// ---------------------------------------------------------------------------
// GEMM1: DOUBLE-buffered LDS + issue-early gload_lds, ONE barrier per K-step:
//   STAGE(kt+1 -> buf^1) ; COMPUTE(buf) ; __syncthreads() ; flip
// Loads for kt+1 fly across the whole compute of kt (m97/T3-minimum schedule;
// round-9's 2-barrier form exposed full load latency each step).
// ---------------------------------------------------------------------------
__global__ __launch_bounds__(256, 2)
void gemm1_kernel(const bf16* __restrict__ Ag, const bf16* __restrict__ w1b,
                  const int* __restrict__ counts, const int* __restrict__ offs,
                  bf16* __restrict__ act)
{
    const int e  = blockIdx.z;
    const int rt = blockIdx.y;
    const int ct = blockIdx.x;              // 0..43
    const int n  = counts[e];
    const int r0 = rt * 128;
    if (r0 >= n) return;
    const int base = offs[e];

    __shared__ __align__(16) bf16 As[2][128*64];
    __shared__ __align__(16) bf16 Bs[2][128*64];
    bf16x8* Asv = (bf16x8*)As;              // buffer stride 1024 bf16x8
    bf16x8* Bsv = (bf16x8*)Bs;

    const int t    = threadIdx.x;
    const int lane = t & 63, wv = t >> 6;
    const int rlow = lane >> 3;             // 0..7
    const int cg   = (lane & 7) ^ rlow;     // pre-swizzled source chunk

    const bf16* aPtr[4];
    const bf16* bPtr[4];
    bf16* aLds[4]; bf16* bLds[4];
    #pragma unroll
    for (int i = 0; i < 4; ++i) {
        int r = wv*32 + i*8 + rlow;         // tile-local row 0..127
        aPtr[i] = Ag + (size_t)(base + r0 + r) * K_DIM + cg*8;
        int w1row = (r < 64) ? (ct*64 + r) : (DFF + ct*64 + (r - 64));
        bPtr[i] = w1b + ((size_t)e*(2*DFF) + w1row) * K_DIM + cg*8;
        aLds[i] = As[0] + (wv*32 + i*8)*64; // wave-uniform linear dest (buf 0)
        bLds[i] = Bs[0] + (wv*32 + i*8)*64;
    }

    const int wr = wv >> 1, wc = wv & 1;
    const int l15 = lane & 15, lq = lane >> 4;

    f32x4 accG[4][2], accU[4][2];
    #pragma unroll
    for (int m = 0; m < 4; ++m)
        #pragma unroll
        for (int nn = 0; nn < 2; ++nn) {
            accG[m][nn] = (f32x4){0.f,0.f,0.f,0.f};
            accU[m][nn] = (f32x4){0.f,0.f,0.f,0.f};
        }

#define G1_STAGE(KT_, B_) do { \
    _Pragma("unroll") for (int i = 0; i < 4; ++i) { \
        gload_lds16(aPtr[i] + (KT_)*64, aLds[i] + (B_)*(128*64)); \
        gload_lds16(bPtr[i] + (KT_)*64, bLds[i] + (B_)*(128*64)); \
    } } while (0)

#define G1_COMPUTE(CUR_) do { \
    _Pragma("unroll") for (int ks = 0; ks < 2; ++ks) { \
        bf16x8 af[4], bg[2], bu[2]; \
        _Pragma("unroll") for (int m = 0; m < 4; ++m) { \
            int fr = wr*64 + m*16 + l15; \
            af[m] = Asv[(CUR_)*1024 + fr*8 + ((ks*4 + lq) ^ (fr & 7))]; \
        } \
        _Pragma("unroll") for (int nn = 0; nn < 2; ++nn) { \
            int frg = wc*32 + nn*16 + l15; \
            bg[nn] = Bsv[(CUR_)*1024 + frg*8 + ((ks*4 + lq) ^ (frg & 7))]; \
            int fru = 64 + wc*32 + nn*16 + l15; \
            bu[nn] = Bsv[(CUR_)*1024 + fru*8 + ((ks*4 + lq) ^ (fru & 7))]; \
        } \
        _Pragma("unroll") for (int m = 0; m < 4; ++m) \
            _Pragma("unroll") for (int nn = 0; nn < 2; ++nn) { \
                accG[m][nn] = __builtin_amdgcn_mfma_f32_16x16x32_bf16(af[m], bg[nn], accG[m][nn], 0, 0, 0); \
                accU[m][nn] = __builtin_amdgcn_mfma_f32_16x16x32_bf16(af[m], bu[nn], accU[m][nn], 0, 0, 0); \
            } \
    } } while (0)

    const int KT = K_DIM / 64;   // 16
    G1_STAGE(0, 0);
    __syncthreads();             // drain tile-0 loads, align waves
    int cur = 0;
    for (int kt = 0; kt < KT; ++kt) {
        if (kt + 1 < KT) G1_STAGE(kt + 1, cur ^ 1);   // issue-early: flies over compute
        G1_COMPUTE(cur);
        __syncthreads();         // vmcnt drain + barrier (one per K-step)
        cur ^= 1;
    }

    // epilogue: act = silu(gate) * up  (C/D: col=lane&15, row=(lane>>4)*4+r)
    #pragma unroll
    for (int m = 0; m < 4; ++m)
        #pragma unroll
        for (int nn = 0; nn < 2; ++nn)
            #pragma unroll
            for (int r = 0; r < 4; ++r) {
                int rl = wr*64 + m*16 + lq*4 + r;
                int grow = r0 + rl;
                if (grow < n) {
                    float g = accG[m][nn][r];
                    float u = accU[m][nn][r];
                    float a = (g / (1.f + __expf(-g))) * u;
                    int col = ct*64 + wc*32 + nn*16 + l15;
                    act[(size_t)(base + grow) * DFF + col] = (bf16)a;
                }
            }
#undef G1_STAGE
#undef G1_COMPUTE
}

// ---------------------------------------------------------------------------
// GEMM2: same double-buffered issue-early schedule; KSPLIT=2; atomic scatter.
// ---------------------------------------------------------------------------
__global__ __launch_bounds__(256, 2)
void gemm2_kernel(const bf16* __restrict__ act, const bf16* __restrict__ w2b,
                  const int* __restrict__ counts, const int* __restrict__ offs,
                  const int* __restrict__ row_token, const float* __restrict__ row_wgt,
                  float* __restrict__ out)
{
    const int e   = blockIdx.z;
    const int rt  = blockIdx.y;
    const int ct  = blockIdx.x >> 1;
    const int ksp = blockIdx.x & 1;
    const int n   = counts[e];
    const int r0  = rt * 128;
    if (r0 >= n) return;
    const int base = offs[e];

    __shared__ __align__(16) bf16 As[2][128*64];
    __shared__ __align__(16) bf16 Bs[2][128*64];
    bf16x8* Asv = (bf16x8*)As;
    bf16x8* Bsv = (bf16x8*)Bs;

    const int t    = threadIdx.x;
    const int lane = t & 63, wv = t >> 6;
    const int rlow = lane >> 3;
    const int cg   = (lane & 7) ^ rlow;

    const bf16* aPtr[4];
    const bf16* bPtr[4];
    bf16* aLds[4]; bf16* bLds[4];
    #pragma unroll
    for (int i = 0; i < 4; ++i) {
        int r = wv*32 + i*8 + rlow;
        aPtr[i] = act + (size_t)(base + r0 + r) * DFF + ksp*(DFF/KSPLIT) + cg*8;
        bPtr[i] = w2b + ((size_t)e*K_DIM + ct*128 + r) * DFF + ksp*(DFF/KSPLIT) + cg*8;
        aLds[i] = As[0] + (wv*32 + i*8)*64;
        bLds[i] = Bs[0] + (wv*32 + i*8)*64;
    }

    const int wr = wv >> 1, wc = wv & 1;
    const int l15 = lane & 15, lq = lane >> 4;

    f32x4 acc[4][4];
    #pragma unroll
    for (int m = 0; m < 4; ++m)
        #pragma unroll
        for (int nn = 0; nn < 4; ++nn) acc[m][nn] = (f32x4){0.f,0.f,0.f,0.f};

#define G2_STAGE(KT_, B_) do { \
    _Pragma("unroll") for (int i = 0; i < 4; ++i) { \
        gload_lds16(aPtr[i] + (KT_)*64, aLds[i] + (B_)*(128*64)); \
        gload_lds16(bPtr[i] + (KT_)*64, bLds[i] + (B_)*(128*64)); \
    } } while (0)

#define G2_COMPUTE(CUR_) do { \
    _Pragma("unroll") for (int ks = 0; ks < 2; ++ks) { \
        bf16x8 af[4], bf[4]; \
        _Pragma("unroll") for (int m = 0; m < 4; ++m) { \
            int fr = wr*64 + m*16 + l15; \
            af[m] = Asv[(CUR_)*1024 + fr*8 + ((ks*4 + lq) ^ (fr & 7))]; \
        } \
        _Pragma("unroll") for (int nn = 0; nn < 4; ++nn) { \
            int fr = wc*64 + nn*16 + l15; \
            bf[nn] = Bsv[(CUR_)*1024 + fr*8 + ((ks*4 + lq) ^ (fr & 7))]; \
        } \
        _Pragma("unroll") for (int m = 0; m < 4; ++m) \
            _Pragma("unroll") for (int nn = 0; nn < 4; ++nn) \
                acc[m][nn] = __builtin_amdgcn_mfma_f32_16x16x32_bf16(af[m], bf[nn], acc[m][nn], 0, 0, 0); \
    } } while (0)

    G2_STAGE(0, 0);
    __syncthreads();
    int cur = 0;
    for (int kt = 0; kt < KT2; ++kt) {
        if (kt + 1 < KT2) G2_STAGE(kt + 1, cur ^ 1);
        G2_COMPUTE(cur);
        __syncthreads();
        cur ^= 1;
    }

    #pragma unroll
    for (int m = 0; m < 4; ++m)
        #pragma unroll
        for (int nn = 0; nn < 4; ++nn)
            #pragma unroll
            for (int r = 0; r < 4; ++r) {
                int rl = wr*64 + m*16 + lq*4 + r;
                int grow = r0 + rl;
                if (grow < n) {
                    int idx = base + grow;
                    int tok   = row_token[idx];
                    float wgt = row_wgt[idx];
                    int col = ct*128 + wc*64 + nn*16 + l15;
                    atomicAdd(out + (size_t)tok * K_DIM + col, wgt * acc[m][nn][r]);
                }
            }
#undef G2_STAGE
#undef G2_COMPUTE
}

// ---------------------------------------------------------------------------
// FALLBACK (reg-staged) — only if ws too small for bf16 mirrors.
// ---------------------------------------------------------------------------
__global__ __launch_bounds__(256, 2)
void gemm1_rs(const float* __restrict__ X, const float* __restrict__ w1,
              const int* __restrict__ counts, const int* __restrict__ offs,
              const int* __restrict__ row_token, bf16* __restrict__ act)
{
    const int e  = blockIdx.z;
    const int rt = blockIdx.y;
    const int ct = blockIdx.x;
    const int n  = counts[e];
    const int r0 = rt * 128;
    if (r0 >= n) return;
    const int base = offs[e];

    __shared__ __align__(16) bf16 As[128*64];
    __shared__ __align__(16) bf16 Bs[128*64];
    bf16x8* Asv = (bf16x8*)As;
    bf16x8* Bsv = (bf16x8*)Bs;

    const int t   = threadIdx.x;
    const int rq0 = t >> 3;
    const int ju  = t & 7;

    const float* aRow[4];
    const float* bRow[4];
    #pragma unroll
    for (int q = 0; q < 4; ++q) {
        int rl = r0 + q*32 + rq0; if (rl > n - 1) rl = n - 1;
        aRow[q] = X + (size_t)row_token[base + rl] * K_DIM + ju*8;
        int brow = q*32 + rq0;
        int w1row = (brow < 64) ? (ct*64 + brow) : (DFF + ct*64 + brow - 64);
        bRow[q] = w1 + ((size_t)e * (2*DFF) + w1row) * K_DIM + ju*8;
    }

    const int lane = t & 63, wv = t >> 6;
    const int wr = wv >> 1, wc = wv & 1;
    const int l15 = lane & 15, lq = lane >> 4;

    f32x4 accG[4][2], accU[4][2];
    #pragma unroll
    for (int m = 0; m < 4; ++m)
        #pragma unroll
        for (int nn = 0; nn < 2; ++nn) {
            accG[m][nn] = (f32x4){0.f,0.f,0.f,0.f};
            accU[m][nn] = (f32x4){0.f,0.f,0.f,0.f};
        }

    f32x4 ra[8], rb[8];

#define G1_LOAD(KT_) do { \
    _Pragma("unroll") for (int q = 0; q < 4; ++q) { \
        const f32x4* ap_ = (const f32x4*)(aRow[q] + (KT_)*64); \
        ra[2*q] = ap_[0]; ra[2*q+1] = ap_[1]; \
        const f32x4* bp_ = (const f32x4*)(bRow[q] + (KT_)*64); \
        rb[2*q] = bp_[0]; rb[2*q+1] = bp_[1]; \
    } } while (0)

#define G1_STORE() do { \
    _Pragma("unroll") for (int q = 0; q < 4; ++q) { \
        int rq_ = q*32 + rq0; \
        f32x4 lo = ra[2*q], hi = ra[2*q+1]; bf16x8 v; \
        _Pragma("unroll") for (int j = 0; j < 4; ++j) { v[j]=(bf16)lo[j]; v[j+4]=(bf16)hi[j]; } \
        Asv[rq_*8 + (ju ^ (rq_ & 7))] = v; \
        f32x4 lo2 = rb[2*q], hi2 = rb[2*q+1]; bf16x8 v2; \
        _Pragma("unroll") for (int j = 0; j < 4; ++j) { v2[j]=(bf16)lo2[j]; v2[j+4]=(bf16)hi2[j]; } \
        Bsv[rq_*8 + (ju ^ (rq_ & 7))] = v2; \
    } } while (0)

#define G1_COMPUTE() do { \
    _Pragma("unroll") for (int ks = 0; ks < 2; ++ks) { \
        bf16x8 af[4], bg[2], bu[2]; \
        _Pragma("unroll") for (int m = 0; m < 4; ++m) { \
            int fr = wr*64 + m*16 + l15; \
            af[m] = Asv[fr*8 + ((ks*4 + lq) ^ (fr & 7))]; \
        } \
        _Pragma("unroll") for (int nn = 0; nn < 2; ++nn) { \
            int frg = wc*32 + nn*16 + l15; \
            bg[nn] = Bsv[frg*8 + ((ks*4 + lq) ^ (frg & 7))]; \
            int fru = 64 + wc*32 + nn*16 + l15; \
            bu[nn] = Bsv[fru*8 + ((ks*4 + lq) ^ (fru & 7))]; \
        } \
        _Pragma("unroll") for (int m = 0; m < 4; ++m) \
            _Pragma("unroll") for (int nn = 0; nn < 2; ++nn) { \
                accG[m][nn] = __builtin_amdgcn_mfma_f32_16x16x32_bf16(af[m], bg[nn], accG[m][nn], 0, 0, 0); \
                accU[m][nn] = __builtin_amdgcn_mfma_f32_16x16x32_bf16(af[m], bu[nn], accU[m][nn], 0, 0, 0); \
            } \
    } } while (0)

    const int KT = K_DIM / 64;
    G1_LOAD(0);
    for (int kt = 0; kt < KT; ++kt) {
        if (kt) __syncthreads();
        G1_STORE();
        if (kt + 1 < KT) G1_LOAD(kt + 1);
        __syncthreads();
        G1_COMPUTE();
    }

    #pragma unroll
    for (int m = 0; m < 4; ++m)
        #pragma unroll
        for (int nn = 0; nn < 2; ++nn)
            #pragma unroll
            for (int r = 0; r < 4; ++r) {
                int rl = wr*64 + m*16 + lq*4 + r;
                int grow = r0 + rl;
                if (grow < n) {
                    float g = accG[m][nn][r];
                    float u = accU[m][nn][r];
                    float a = (g / (1.f + __expf(-g))) * u;
                    int col = ct*64 + wc*32 + nn*16 + l15;
                    act[(size_t)(base + grow) * DFF + col] = (bf16)a;
                }
            }
#undef G1_LOAD
#undef G1_STORE
#undef G1_COMPUTE
}

__global__ __launch_bounds__(256, 2)
void gemm2_rs(const bf16* __restrict__ act, const float* __restrict__ w2,
              const int* __restrict__ counts, const int* __restrict__ offs,
              const int* __restrict__ row_token, const float* __restrict__ row_wgt,
              float* __restrict__ out)
{
    const int e   = blockIdx.z;
    const int rt  = blockIdx.y;
    const int ct  = blockIdx.x >> 1;
    const int ksp = blockIdx.x & 1;
    const int n   = counts[e];
    const int r0  = rt * 128;
    if (r0 >= n) return;
    const int base = offs[e];

    __shared__ __align__(16) bf16 As[128*64];
    __shared__ __align__(16) bf16 Bs[128*64];
    bf16x8* Asv = (bf16x8*)As;
    bf16x8* Bsv = (bf16x8*)Bs;

    const int t = threadIdx.x;
    const int rqa = t >> 2, jua = t & 3;
    const int rqb = t >> 3, jub = t & 7;

    const bf16* aRow[2];
    #pragma unroll
    for (int q = 0; q < 2; ++q) {
        int rl = r0 + q*64 + rqa; if (rl > n - 1) rl = n - 1;
        aRow[q] = act + (size_t)(base + rl) * DFF + ksp*(DFF/KSPLIT) + jua*16;
    }
    const float* bRow[4];
    #pragma unroll
    for (int q = 0; q < 4; ++q) {
        int brow = ct*128 + q*32 + rqb;
        bRow[q] = w2 + ((size_t)e * K_DIM + brow) * DFF + ksp*(DFF/KSPLIT) + jub*8;
    }

    const int lane = t & 63, wv = t >> 6;
    const int wr = wv >> 1, wc = wv & 1;
    const int l15 = lane & 15, lq = lane >> 4;

    f32x4 acc[4][4];
    #pragma unroll
    for (int m = 0; m < 4; ++m)
        #pragma unroll
        for (int nn = 0; nn < 4; ++nn) acc[m][nn] = (f32x4){0.f,0.f,0.f,0.f};

    bf16x8 qa[4];
    f32x4  rb[8];

#define G2_LOAD(KT_) do { \
    _Pragma("unroll") for (int q = 0; q < 2; ++q) { \
        const bf16x8* ap_ = (const bf16x8*)(aRow[q] + (KT_)*64); \
        qa[2*q] = ap_[0]; qa[2*q+1] = ap_[1]; \
    } \
    _Pragma("unroll") for (int q = 0; q < 4; ++q) { \
        const f32x4* bp_ = (const f32x4*)(bRow[q] + (KT_)*64); \
        rb[2*q] = bp_[0]; rb[2*q+1] = bp_[1]; \
    } } while (0)

#define G2_STORE() do { \
    _Pragma("unroll") for (int q = 0; q < 2; ++q) { \
        int ra_ = q*64 + rqa; \
        Asv[ra_*8 + ((2*jua)   ^ (ra_ & 7))] = qa[2*q]; \
        Asv[ra_*8 + ((2*jua+1) ^ (ra_ & 7))] = qa[2*q+1]; \
    } \
    _Pragma("unroll") for (int q = 0; q < 4; ++q) { \
        int rb_ = q*32 + rqb; \
        f32x4 lo = rb[2*q], hi = rb[2*q+1]; bf16x8 v; \
        _Pragma("unroll") for (int j = 0; j < 4; ++j) { v[j]=(bf16)lo[j]; v[j+4]=(bf16)hi[j]; } \
        Bsv[rb_*8 + (jub ^ (rb_ & 7))] = v; \
    } } while (0)

#define G2_COMPUTE() do { \
    _Pragma("unroll") for (int ks = 0; ks < 2; ++ks) { \
        bf16x8 af[4], bf[4]; \
        _Pragma("unroll") for (int m = 0; m < 4; ++m) { \
            int fr = wr*64 + m*16 + l15; \
            af[m] = Asv[fr*8 + ((ks*4 + lq) ^ (fr & 7))]; \
        } \
        _Pragma("unroll") for (int nn = 0; nn < 4; ++nn) { \
            int fr = wc*64 + nn*16 + l15; \
            bf[nn] = Bsv[fr*8 + ((ks*4 + lq) ^ (fr & 7))]; \
        } \
        _Pragma("unroll") for (int m = 0; m < 4; ++m) \
            _Pragma("unroll") for (int nn = 0; nn < 4; ++nn) \
                acc[m][nn] = __builtin_amdgcn_mfma_f32_16x16x32_bf16(af[m], bf[nn], acc[m][nn], 0, 0, 0); \
    } } while (0)

    G2_LOAD(0);
    for (int kt = 0; kt < KT2; ++kt) {
        if (kt) __syncthreads();
        G2_STORE();
        if (kt + 1 < KT2) G2_LOAD(kt + 1);
        __syncthreads();
        G2_COMPUTE();
    }

    #pragma unroll
    for (int m = 0; m < 4; ++m)
        #pragma unroll
        for (int nn = 0; nn < 4; ++nn)
            #pragma unroll
            for (int r = 0; r < 4; ++r) {
                int rl = wr*64 + m*16 + lq*4 + r;
                int grow = r0 + rl;
                if (grow < n) {
                    int idx = base + grow;
                    int tok   = row_token[idx];
                    float wgt = row_wgt[idx];
                    int col = ct*128 + wc*64 + nn*16 + l15;
                    atomicAdd(out + (size_t)tok * K_DIM + col, wgt * acc[m][nn][r]);
                }
            }
#undef G2_LOAD
#undef G2_STORE
#undef G2_COMPUTE
}

// ---------------------------------------------------------------------------
extern "C" void kernel_launch(void* const* d_in, const int* in_sizes, int n_in,
                              void* d_out, int out_size, void* d_ws, size_t ws_size,
                              hipStream_t stream)
{
    const float* X   = (const float*)d_in[0];
    const float* w1  = (const float*)d_in[1];
    const float* w2  = (const float*)d_in[2];
    const float* tw  = (const float*)d_in[3];
    const int*   ids = (const int*)d_in[4];
    float* out = (float*)d_out;

    // ws layout: act | row_token | row_wgt | counts | offs | Ag | w1b | w2b
    char* p = (char*)d_ws;
    bf16*  act       = (bf16*)p;   p += (size_t)NROWS * DFF * 2;
    int*   row_token = (int*)p;    p += (size_t)NROWS * 4;
    float* row_wgt   = (float*)p;  p += (size_t)NROWS * 4;
    int*   counts    = (int*)p;    p += 32;
    int*   offs      = (int*)p;    p += 32;
    bf16*  Ag        = (bf16*)p;   p += (size_t)NROWS * K_DIM * 2;
    bf16*  w1b       = (bf16*)p;   p += (size_t)E_NUM * 2*DFF * K_DIM * 2;
    bf16*  w2b       = (bf16*)p;   p += (size_t)E_NUM * K_DIM * DFF * 2;
    const size_t NEEDED = (size_t)(p - (char*)d_ws);   // ~162 MiB

    zero_kernel<<<512, 256, 0, stream>>>(out, out_size / 4);
    route_kernel<<<1, 512, 0, stream>>>(ids, tw, counts, offs, row_token, row_wgt);

    if (ws_size >= NEEDED) {
        cast2_kernel<<<4096, 256, 0, stream>>>(w1, w1b, (long)E_NUM * 2*DFF * K_DIM / 8,
                                               w2, w2b, (long)E_NUM * K_DIM * DFF / 8);
        gather_cast_kernel<<<NROWS, 256, 0, stream>>>(X, row_token, Ag);
        gemm1_kernel<<<dim3(DFF/64, NROWS/128, E_NUM), 256, 0, stream>>>(Ag, w1b, counts, offs, act);
        gemm2_kernel<<<dim3((K_DIM/128)*KSPLIT, NROWS/128, E_NUM), 256, 0, stream>>>(act, w2b, counts, offs, row_token, row_wgt, out);
    } else {
        gemm1_rs<<<dim3(DFF/64, NROWS/128, E_NUM), 256, 0, stream>>>(X, w1, counts, offs, row_token, act);
        gemm2_rs<<<dim3((K_DIM/128)*KSPLIT, NROWS/128, E_NUM), 256, 0, stream>>>(act, w2, counts, offs, row_token, row_wgt, out);
    }
}

// Round 11
// 309.909 us; speedup vs baseline: 1.1074x; 1.1074x over previous
//
#include <hip/hip_runtime.h>
#include <hip/hip_bf16.h>

#define M_TOK 2048
#define K_DIM 1024
#define E_NUM 8
#define DFF   2816
#define TOPK  2
#define NROWS (M_TOK*TOPK)   // 4096 routed rows
#define KSPLIT 4
#define KT2    (DFF / 64 / KSPLIT)   // 11

typedef __bf16 bf16;
typedef __bf16 bf16x8 __attribute__((ext_vector_type(8)));
typedef __bf16 bf16x4 __attribute__((ext_vector_type(4)));
typedef float  f32x4  __attribute__((ext_vector_type(4)));

__device__ __forceinline__ void gload_lds16(const bf16* g, bf16* l) {
    __builtin_amdgcn_global_load_lds(
        (const __attribute__((address_space(1))) void*)g,
        (__attribute__((address_space(3))) void*)l, 16, 0, 0);
}

// ---------------------------------------------------------------------------
// Zero d_out (grid-stride f32x4).
// ---------------------------------------------------------------------------
__global__ __launch_bounds__(256)
void zero_kernel(float* __restrict__ p, int n4)
{
    int i = blockIdx.x * 256 + threadIdx.x;
    int stride = gridDim.x * 256;
    f32x4 z = (f32x4){0.f, 0.f, 0.f, 0.f};
    for (; i < n4; i += stride) ((f32x4*)p)[i] = z;
}

// ---------------------------------------------------------------------------
// Routing (unchanged, verified).
// ---------------------------------------------------------------------------
__global__ __launch_bounds__(512)
void route_kernel(const int* __restrict__ ids,
                  const float* __restrict__ tw,
                  int* __restrict__ counts, int* __restrict__ offs,
                  int* __restrict__ row_token, float* __restrict__ row_wgt)
{
    const int e    = threadIdx.x >> 6;
    const int lane = threadIdx.x & 63;
    __shared__ int scnt[E_NUM];

    int cnt = 0;
    for (int i0 = 0; i0 < NROWS; i0 += 64) {
        int id = ids[i0 + lane];
        cnt += __popcll(__ballot(id == e));
    }
    if (lane == 0) scnt[e] = cnt;
    __syncthreads();
    int base = 0;
    for (int j = 0; j < e; ++j) base += scnt[j];
    if (lane == 0) { counts[e] = cnt; offs[e] = base; }

    const unsigned long long ltmask = (1ull << lane) - 1ull;
    int pos = base;
    for (int i0 = 0; i0 < NROWS; i0 += 64) {
        int i = i0 + lane;
        int id = ids[i];
        unsigned long long m = __ballot(id == e);
        if (id == e) {
            int rank = __popcll(m & ltmask);
            row_token[pos + rank] = i >> 1;
            row_wgt[pos + rank]   = tw[i];
        }
        pos += __popcll(m);
    }
}

// ---------------------------------------------------------------------------
// fp32 -> bf16 cast for BOTH weight tensors in one launch.
// ---------------------------------------------------------------------------
__global__ __launch_bounds__(256)
void cast2_kernel(const float* __restrict__ s1, bf16* __restrict__ d1, long n1_8,
                  const float* __restrict__ s2, bf16* __restrict__ d2, long n2_8)
{
    long i = (long)blockIdx.x * 256 + threadIdx.x;
    long stride = (long)gridDim.x * 256;
    long ntot = n1_8 + n2_8;
    for (; i < ntot; i += stride) {
        const float* s; bf16* d; long j;
        if (i < n1_8) { s = s1; d = d1; j = i; }
        else          { s = s2; d = d2; j = i - n1_8; }
        f32x4 a = ((const f32x4*)s)[2*j];
        f32x4 b = ((const f32x4*)s)[2*j + 1];
        bf16x8 v;
        #pragma unroll
        for (int k = 0; k < 4; ++k) { v[k] = (bf16)a[k]; v[k+4] = (bf16)b[k]; }
        ((bf16x8*)d)[j] = v;
    }
}

// ---------------------------------------------------------------------------
// Gather routed rows of X and cast to bf16.
// ---------------------------------------------------------------------------
__global__ __launch_bounds__(256)
void gather_cast_kernel(const float* __restrict__ X, const int* __restrict__ row_token,
                        bf16* __restrict__ Ag)
{
    const int row = blockIdx.x;
    const int tok = row_token[row];
    f32x4 a = ((const f32x4*)(X + (size_t)tok * K_DIM))[threadIdx.x];
    bf16x4 v;
    #pragma unroll
    for (int j = 0; j < 4; ++j) v[j] = (bf16)a[j];
    ((bf16x4*)(Ag + (size_t)row * K_DIM))[threadIdx.x] = v;
}

// ---------------------------------------------------------------------------
// GEMM1: gload_lds staging, SINGLE 32KiB buffer, 2 barriers/step,
// __launch_bounds__(256,4): 4 blocks/CU (16 waves) — TLP is the latency cover.
// gload_lds means no staging VGPRs: ~88 regs fits the 128/wave budget at 4/EU.
// ---------------------------------------------------------------------------
__global__ __launch_bounds__(256, 4)
void gemm1_kernel(const bf16* __restrict__ Ag, const bf16* __restrict__ w1b,
                  const int* __restrict__ counts, const int* __restrict__ offs,
                  bf16* __restrict__ act)
{
    const int e  = blockIdx.z;
    const int rt = blockIdx.y;
    const int ct = blockIdx.x;              // 0..43
    const int n  = counts[e];
    const int r0 = rt * 128;
    if (r0 >= n) return;
    const int base = offs[e];

    __shared__ __align__(16) bf16 As[128*64];
    __shared__ __align__(16) bf16 Bs[128*64];
    bf16x8* Asv = (bf16x8*)As;
    bf16x8* Bsv = (bf16x8*)Bs;

    const int t    = threadIdx.x;
    const int lane = t & 63, wv = t >> 6;
    const int rlow = lane >> 3;             // 0..7
    const int cg   = (lane & 7) ^ rlow;     // pre-swizzled source chunk

    const bf16* aPtr[4];
    const bf16* bPtr[4];
    bf16* aLds[4]; bf16* bLds[4];
    #pragma unroll
    for (int i = 0; i < 4; ++i) {
        int r = wv*32 + i*8 + rlow;         // tile-local row 0..127
        aPtr[i] = Ag + (size_t)(base + r0 + r) * K_DIM + cg*8;
        int w1row = (r < 64) ? (ct*64 + r) : (DFF + ct*64 + (r - 64));
        bPtr[i] = w1b + ((size_t)e*(2*DFF) + w1row) * K_DIM + cg*8;
        aLds[i] = As + (wv*32 + i*8)*64;    // wave-uniform linear dest
        bLds[i] = Bs + (wv*32 + i*8)*64;
    }

    const int wr = wv >> 1, wc = wv & 1;
    const int l15 = lane & 15, lq = lane >> 4;

    f32x4 accG[4][2], accU[4][2];
    #pragma unroll
    for (int m = 0; m < 4; ++m)
        #pragma unroll
        for (int nn = 0; nn < 2; ++nn) {
            accG[m][nn] = (f32x4){0.f,0.f,0.f,0.f};
            accU[m][nn] = (f32x4){0.f,0.f,0.f,0.f};
        }

#define G1_STAGE(KT_) do { \
    _Pragma("unroll") for (int i = 0; i < 4; ++i) { \
        gload_lds16(aPtr[i] + (KT_)*64, aLds[i]); \
        gload_lds16(bPtr[i] + (KT_)*64, bLds[i]); \
    } } while (0)

#define G1_COMPUTE() do { \
    _Pragma("unroll") for (int ks = 0; ks < 2; ++ks) { \
        bf16x8 af[4], bg[2], bu[2]; \
        _Pragma("unroll") for (int m = 0; m < 4; ++m) { \
            int fr = wr*64 + m*16 + l15; \
            af[m] = Asv[fr*8 + ((ks*4 + lq) ^ (fr & 7))]; \
        } \
        _Pragma("unroll") for (int nn = 0; nn < 2; ++nn) { \
            int frg = wc*32 + nn*16 + l15; \
            bg[nn] = Bsv[frg*8 + ((ks*4 + lq) ^ (frg & 7))]; \
            int fru = 64 + wc*32 + nn*16 + l15; \
            bu[nn] = Bsv[fru*8 + ((ks*4 + lq) ^ (fru & 7))]; \
        } \
        _Pragma("unroll") for (int m = 0; m < 4; ++m) \
            _Pragma("unroll") for (int nn = 0; nn < 2; ++nn) { \
                accG[m][nn] = __builtin_amdgcn_mfma_f32_16x16x32_bf16(af[m], bg[nn], accG[m][nn], 0, 0, 0); \
                accU[m][nn] = __builtin_amdgcn_mfma_f32_16x16x32_bf16(af[m], bu[nn], accU[m][nn], 0, 0, 0); \
            } \
    } } while (0)

    const int KT = K_DIM / 64;   // 16
    G1_STAGE(0);
    for (int kt = 0; kt < KT; ++kt) {
        __syncthreads();                    // drain vmcnt + barrier
        G1_COMPUTE();
        if (kt + 1 < KT) { __syncthreads(); G1_STAGE(kt + 1); }
    }

    // epilogue: act = silu(gate) * up  (C/D: col=lane&15, row=(lane>>4)*4+r)
    #pragma unroll
    for (int m = 0; m < 4; ++m)
        #pragma unroll
        for (int nn = 0; nn < 2; ++nn)
            #pragma unroll
            for (int r = 0; r < 4; ++r) {
                int rl = wr*64 + m*16 + lq*4 + r;
                int grow = r0 + rl;
                if (grow < n) {
                    float g = accG[m][nn][r];
                    float u = accU[m][nn][r];
                    float a = (g / (1.f + __expf(-g))) * u;
                    int col = ct*64 + wc*32 + nn*16 + l15;
                    act[(size_t)(base + grow) * DFF + col] = (bf16)a;
                }
            }
#undef G1_STAGE
#undef G1_COMPUTE
}

// ---------------------------------------------------------------------------
// GEMM2: same structure; KSPLIT=4 (1024 blocks) so 4 blocks/CU is reachable.
// ---------------------------------------------------------------------------
__global__ __launch_bounds__(256, 4)
void gemm2_kernel(const bf16* __restrict__ act, const bf16* __restrict__ w2b,
                  const int* __restrict__ counts, const int* __restrict__ offs,
                  const int* __restrict__ row_token, const float* __restrict__ row_wgt,
                  float* __restrict__ out)
{
    const int e   = blockIdx.z;
    const int rt  = blockIdx.y;
    const int ct  = blockIdx.x >> 2;          // 0..7 : 128 out cols
    const int ksp = blockIdx.x & 3;           // DFF quarter
    const int n   = counts[e];
    const int r0  = rt * 128;
    if (r0 >= n) return;
    const int base = offs[e];

    __shared__ __align__(16) bf16 As[128*64];
    __shared__ __align__(16) bf16 Bs[128*64];
    bf16x8* Asv = (bf16x8*)As;
    bf16x8* Bsv = (bf16x8*)Bs;

    const int t    = threadIdx.x;
    const int lane = t & 63, wv = t >> 6;
    const int rlow = lane >> 3;
    const int cg   = (lane & 7) ^ rlow;

    const bf16* aPtr[4];
    const bf16* bPtr[4];
    bf16* aLds[4]; bf16* bLds[4];
    #pragma unroll
    for (int i = 0; i < 4; ++i) {
        int r = wv*32 + i*8 + rlow;
        aPtr[i] = act + (size_t)(base + r0 + r) * DFF + ksp*(DFF/KSPLIT) + cg*8;
        bPtr[i] = w2b + ((size_t)e*K_DIM + ct*128 + r) * DFF + ksp*(DFF/KSPLIT) + cg*8;
        aLds[i] = As + (wv*32 + i*8)*64;
        bLds[i] = Bs + (wv*32 + i*8)*64;
    }

    const int wr = wv >> 1, wc = wv & 1;
    const int l15 = lane & 15, lq = lane >> 4;

    f32x4 acc[4][4];
    #pragma unroll
    for (int m = 0; m < 4; ++m)
        #pragma unroll
        for (int nn = 0; nn < 4; ++nn) acc[m][nn] = (f32x4){0.f,0.f,0.f,0.f};

#define G2_STAGE(KT_) do { \
    _Pragma("unroll") for (int i = 0; i < 4; ++i) { \
        gload_lds16(aPtr[i] + (KT_)*64, aLds[i]); \
        gload_lds16(bPtr[i] + (KT_)*64, bLds[i]); \
    } } while (0)

#define G2_COMPUTE() do { \
    _Pragma("unroll") for (int ks = 0; ks < 2; ++ks) { \
        bf16x8 af[4], bf[4]; \
        _Pragma("unroll") for (int m = 0; m < 4; ++m) { \
            int fr = wr*64 + m*16 + l15; \
            af[m] = Asv[fr*8 + ((ks*4 + lq) ^ (fr & 7))]; \
        } \
        _Pragma("unroll") for (int nn = 0; nn < 4; ++nn) { \
            int fr = wc*64 + nn*16 + l15; \
            bf[nn] = Bsv[fr*8 + ((ks*4 + lq) ^ (fr & 7))]; \
        } \
        _Pragma("unroll") for (int m = 0; m < 4; ++m) \
            _Pragma("unroll") for (int nn = 0; nn < 4; ++nn) \
                acc[m][nn] = __builtin_amdgcn_mfma_f32_16x16x32_bf16(af[m], bf[nn], acc[m][nn], 0, 0, 0); \
    } } while (0)

    G2_STAGE(0);
    for (int kt = 0; kt < KT2; ++kt) {
        __syncthreads();
        G2_COMPUTE();
        if (kt + 1 < KT2) { __syncthreads(); G2_STAGE(kt + 1); }
    }

    #pragma unroll
    for (int m = 0; m < 4; ++m)
        #pragma unroll
        for (int nn = 0; nn < 4; ++nn)
            #pragma unroll
            for (int r = 0; r < 4; ++r) {
                int rl = wr*64 + m*16 + lq*4 + r;
                int grow = r0 + rl;
                if (grow < n) {
                    int idx = base + grow;
                    int tok   = row_token[idx];
                    float wgt = row_wgt[idx];
                    int col = ct*128 + wc*64 + nn*16 + l15;
                    atomicAdd(out + (size_t)tok * K_DIM + col, wgt * acc[m][nn][r]);
                }
            }
#undef G2_STAGE
#undef G2_COMPUTE
}

// ---------------------------------------------------------------------------
// FALLBACK (reg-staged, launch_bounds(256,2)) — only if ws too small.
// ---------------------------------------------------------------------------
__global__ __launch_bounds__(256, 2)
void gemm1_rs(const float* __restrict__ X, const float* __restrict__ w1,
              const int* __restrict__ counts, const int* __restrict__ offs,
              const int* __restrict__ row_token, bf16* __restrict__ act)
{
    const int e  = blockIdx.z;
    const int rt = blockIdx.y;
    const int ct = blockIdx.x;
    const int n  = counts[e];
    const int r0 = rt * 128;
    if (r0 >= n) return;
    const int base = offs[e];

    __shared__ __align__(16) bf16 As[128*64];
    __shared__ __align__(16) bf16 Bs[128*64];
    bf16x8* Asv = (bf16x8*)As;
    bf16x8* Bsv = (bf16x8*)Bs;

    const int t   = threadIdx.x;
    const int rq0 = t >> 3;
    const int ju  = t & 7;

    const float* aRow[4];
    const float* bRow[4];
    #pragma unroll
    for (int q = 0; q < 4; ++q) {
        int rl = r0 + q*32 + rq0; if (rl > n - 1) rl = n - 1;
        aRow[q] = X + (size_t)row_token[base + rl] * K_DIM + ju*8;
        int brow = q*32 + rq0;
        int w1row = (brow < 64) ? (ct*64 + brow) : (DFF + ct*64 + brow - 64);
        bRow[q] = w1 + ((size_t)e * (2*DFF) + w1row) * K_DIM + ju*8;
    }

    const int lane = t & 63, wv = t >> 6;
    const int wr = wv >> 1, wc = wv & 1;
    const int l15 = lane & 15, lq = lane >> 4;

    f32x4 accG[4][2], accU[4][2];
    #pragma unroll
    for (int m = 0; m < 4; ++m)
        #pragma unroll
        for (int nn = 0; nn < 2; ++nn) {
            accG[m][nn] = (f32x4){0.f,0.f,0.f,0.f};
            accU[m][nn] = (f32x4){0.f,0.f,0.f,0.f};
        }

    f32x4 ra[8], rb[8];

#define G1_LOAD(KT_) do { \
    _Pragma("unroll") for (int q = 0; q < 4; ++q) { \
        const f32x4* ap_ = (const f32x4*)(aRow[q] + (KT_)*64); \
        ra[2*q] = ap_[0]; ra[2*q+1] = ap_[1]; \
        const f32x4* bp_ = (const f32x4*)(bRow[q] + (KT_)*64); \
        rb[2*q] = bp_[0]; rb[2*q+1] = bp_[1]; \
    } } while (0)

#define G1_STORE() do { \
    _Pragma("unroll") for (int q = 0; q < 4; ++q) { \
        int rq_ = q*32 + rq0; \
        f32x4 lo = ra[2*q], hi = ra[2*q+1]; bf16x8 v; \
        _Pragma("unroll") for (int j = 0; j < 4; ++j) { v[j]=(bf16)lo[j]; v[j+4]=(bf16)hi[j]; } \
        Asv[rq_*8 + (ju ^ (rq_ & 7))] = v; \
        f32x4 lo2 = rb[2*q], hi2 = rb[2*q+1]; bf16x8 v2; \
        _Pragma("unroll") for (int j = 0; j < 4; ++j) { v2[j]=(bf16)lo2[j]; v2[j+4]=(bf16)hi2[j]; } \
        Bsv[rq_*8 + (ju ^ (rq_ & 7))] = v2; \
    } } while (0)

#define G1_COMPUTE() do { \
    _Pragma("unroll") for (int ks = 0; ks < 2; ++ks) { \
        bf16x8 af[4], bg[2], bu[2]; \
        _Pragma("unroll") for (int m = 0; m < 4; ++m) { \
            int fr = wr*64 + m*16 + l15; \
            af[m] = Asv[fr*8 + ((ks*4 + lq) ^ (fr & 7))]; \
        } \
        _Pragma("unroll") for (int nn = 0; nn < 2; ++nn) { \
            int frg = wc*32 + nn*16 + l15; \
            bg[nn] = Bsv[frg*8 + ((ks*4 + lq) ^ (frg & 7))]; \
            int fru = 64 + wc*32 + nn*16 + l15; \
            bu[nn] = Bsv[fru*8 + ((ks*4 + lq) ^ (fru & 7))]; \
        } \
        _Pragma("unroll") for (int m = 0; m < 4; ++m) \
            _Pragma("unroll") for (int nn = 0; nn < 2; ++nn) { \
                accG[m][nn] = __builtin_amdgcn_mfma_f32_16x16x32_bf16(af[m], bg[nn], accG[m][nn], 0, 0, 0); \
                accU[m][nn] = __builtin_amdgcn_mfma_f32_16x16x32_bf16(af[m], bu[nn], accU[m][nn], 0, 0, 0); \
            } \
    } } while (0)

    const int KT = K_DIM / 64;
    G1_LOAD(0);
    for (int kt = 0; kt < KT; ++kt) {
        if (kt) __syncthreads();
        G1_STORE();
        if (kt + 1 < KT) G1_LOAD(kt + 1);
        __syncthreads();
        G1_COMPUTE();
    }

    #pragma unroll
    for (int m = 0; m < 4; ++m)
        #pragma unroll
        for (int nn = 0; nn < 2; ++nn)
            #pragma unroll
            for (int r = 0; r < 4; ++r) {
                int rl = wr*64 + m*16 + lq*4 + r;
                int grow = r0 + rl;
                if (grow < n) {
                    float g = accG[m][nn][r];
                    float u = accU[m][nn][r];
                    float a = (g / (1.f + __expf(-g))) * u;
                    int col = ct*64 + wc*32 + nn*16 + l15;
                    act[(size_t)(base + grow) * DFF + col] = (bf16)a;
                }
            }
#undef G1_LOAD
#undef G1_STORE
#undef G1_COMPUTE
}

__global__ __launch_bounds__(256, 2)
void gemm2_rs(const bf16* __restrict__ act, const float* __restrict__ w2,
              const int* __restrict__ counts, const int* __restrict__ offs,
              const int* __restrict__ row_token, const float* __restrict__ row_wgt,
              float* __restrict__ out)
{
    const int e   = blockIdx.z;
    const int rt  = blockIdx.y;
    const int ct  = blockIdx.x >> 2;
    const int ksp = blockIdx.x & 3;
    const int n   = counts[e];
    const int r0  = rt * 128;
    if (r0 >= n) return;
    const int base = offs[e];

    __shared__ __align__(16) bf16 As[128*64];
    __shared__ __align__(16) bf16 Bs[128*64];
    bf16x8* Asv = (bf16x8*)As;
    bf16x8* Bsv = (bf16x8*)Bs;

    const int t = threadIdx.x;
    const int rqa = t >> 2, jua = t & 3;
    const int rqb = t >> 3, jub = t & 7;

    const bf16* aRow[2];
    #pragma unroll
    for (int q = 0; q < 2; ++q) {
        int rl = r0 + q*64 + rqa; if (rl > n - 1) rl = n - 1;
        aRow[q] = act + (size_t)(base + rl) * DFF + ksp*(DFF/KSPLIT) + jua*16;
    }
    const float* bRow[4];
    #pragma unroll
    for (int q = 0; q < 4; ++q) {
        int brow = ct*128 + q*32 + rqb;
        bRow[q] = w2 + ((size_t)e * K_DIM + brow) * DFF + ksp*(DFF/KSPLIT) + jub*8;
    }

    const int lane = t & 63, wv = t >> 6;
    const int wr = wv >> 1, wc = wv & 1;
    const int l15 = lane & 15, lq = lane >> 4;

    f32x4 acc[4][4];
    #pragma unroll
    for (int m = 0; m < 4; ++m)
        #pragma unroll
        for (int nn = 0; nn < 4; ++nn) acc[m][nn] = (f32x4){0.f,0.f,0.f,0.f};

    bf16x8 qa[4];
    f32x4  rb[8];

#define G2_LOAD(KT_) do { \
    _Pragma("unroll") for (int q = 0; q < 2; ++q) { \
        const bf16x8* ap_ = (const bf16x8*)(aRow[q] + (KT_)*64); \
        qa[2*q] = ap_[0]; qa[2*q+1] = ap_[1]; \
    } \
    _Pragma("unroll") for (int q = 0; q < 4; ++q) { \
        const f32x4* bp_ = (const f32x4*)(bRow[q] + (KT_)*64); \
        rb[2*q] = bp_[0]; rb[2*q+1] = bp_[1]; \
    } } while (0)

#define G2_STORE() do { \
    _Pragma("unroll") for (int q = 0; q < 2; ++q) { \
        int ra_ = q*64 + rqa; \
        Asv[ra_*8 + ((2*jua)   ^ (ra_ & 7))] = qa[2*q]; \
        Asv[ra_*8 + ((2*jua+1) ^ (ra_ & 7))] = qa[2*q+1]; \
    } \
    _Pragma("unroll") for (int q = 0; q < 4; ++q) { \
        int rb_ = q*32 + rqb; \
        f32x4 lo = rb[2*q], hi = rb[2*q+1]; bf16x8 v; \
        _Pragma("unroll") for (int j = 0; j < 4; ++j) { v[j]=(bf16)lo[j]; v[j+4]=(bf16)hi[j]; } \
        Bsv[rb_*8 + (jub ^ (rb_ & 7))] = v; \
    } } while (0)

#define G2_COMPUTE() do { \
    _Pragma("unroll") for (int ks = 0; ks < 2; ++ks) { \
        bf16x8 af[4], bf[4]; \
        _Pragma("unroll") for (int m = 0; m < 4; ++m) { \
            int fr = wr*64 + m*16 + l15; \
            af[m] = Asv[fr*8 + ((ks*4 + lq) ^ (fr & 7))]; \
        } \
        _Pragma("unroll") for (int nn = 0; nn < 4; ++nn) { \
            int fr = wc*64 + nn*16 + l15; \
            bf[nn] = Bsv[fr*8 + ((ks*4 + lq) ^ (fr & 7))]; \
        } \
        _Pragma("unroll") for (int m = 0; m < 4; ++m) \
            _Pragma("unroll") for (int nn = 0; nn < 4; ++nn) \
                acc[m][nn] = __builtin_amdgcn_mfma_f32_16x16x32_bf16(af[m], bf[nn], acc[m][nn], 0, 0, 0); \
    } } while (0)

    G2_LOAD(0);
    for (int kt = 0; kt < KT2; ++kt) {
        if (kt) __syncthreads();
        G2_STORE();
        if (kt + 1 < KT2) G2_LOAD(kt + 1);
        __syncthreads();
        G2_COMPUTE();
    }

    #pragma unroll
    for (int m = 0; m < 4; ++m)
        #pragma unroll
        for (int nn = 0; nn < 4; ++nn)
            #pragma unroll
            for (int r = 0; r < 4; ++r) {
                int rl = wr*64 + m*16 + lq*4 + r;
                int grow = r0 + rl;
                if (grow < n) {
                    int idx = base + grow;
                    int tok   = row_token[idx];
                    float wgt = row_wgt[idx];
                    int col = ct*128 + wc*64 + nn*16 + l15;
                    atomicAdd(out + (size_t)tok * K_DIM + col, wgt * acc[m][nn][r]);
                }
            }
#undef G2_LOAD
#undef G2_STORE
#undef G2_COMPUTE
}

// ---------------------------------------------------------------------------
extern "C" void kernel_launch(void* const* d_in, const int* in_sizes, int n_in,
                              void* d_out, int out_size, void* d_ws, size_t ws_size,
                              hipStream_t stream)
{
    const float* X   = (const float*)d_in[0];
    const float* w1  = (const float*)d_in[1];
    const float* w2  = (const float*)d_in[2];
    const float* tw  = (const float*)d_in[3];
    const int*   ids = (const int*)d_in[4];
    float* out = (float*)d_out;

    // ws layout: act | row_token | row_wgt | counts | offs | Ag | w1b | w2b
    char* p = (char*)d_ws;
    bf16*  act       = (bf16*)p;   p += (size_t)NROWS * DFF * 2;
    int*   row_token = (int*)p;    p += (size_t)NROWS * 4;
    float* row_wgt   = (float*)p;  p += (size_t)NROWS * 4;
    int*   counts    = (int*)p;    p += 32;
    int*   offs      = (int*)p;    p += 32;
    bf16*  Ag        = (bf16*)p;   p += (size_t)NROWS * K_DIM * 2;
    bf16*  w1b       = (bf16*)p;   p += (size_t)E_NUM * 2*DFF * K_DIM * 2;
    bf16*  w2b       = (bf16*)p;   p += (size_t)E_NUM * K_DIM * DFF * 2;
    const size_t NEEDED = (size_t)(p - (char*)d_ws);   // ~162 MiB

    zero_kernel<<<512, 256, 0, stream>>>(out, out_size / 4);
    route_kernel<<<1, 512, 0, stream>>>(ids, tw, counts, offs, row_token, row_wgt);

    if (ws_size >= NEEDED) {
        cast2_kernel<<<4096, 256, 0, stream>>>(w1, w1b, (long)E_NUM * 2*DFF * K_DIM / 8,
                                               w2, w2b, (long)E_NUM * K_DIM * DFF / 8);
        gather_cast_kernel<<<NROWS, 256, 0, stream>>>(X, row_token, Ag);
        gemm1_kernel<<<dim3(DFF/64, NROWS/128, E_NUM), 256, 0, stream>>>(Ag, w1b, counts, offs, act);
        gemm2_kernel<<<dim3((K_DIM/128)*KSPLIT, NROWS/128, E_NUM), 256, 0, stream>>>(act, w2b, counts, offs, row_token, row_wgt, out);
    } else {
        gemm1_rs<<<dim3(DFF/64, NROWS/128, E_NUM), 256, 0, stream>>>(X, w1, counts, offs, row_token, act);
        gemm2_rs<<<dim3((K_DIM/128)*KSPLIT, NROWS/128, E_NUM), 256, 0, stream>>>(act, w2, counts, offs, row_token, row_wgt, out);
    }
}

// Round 12
// 263.781 us; speedup vs baseline: 1.3010x; 1.1749x over previous
//
#include <hip/hip_runtime.h>
#include <hip/hip_bf16.h>

#define M_TOK 2048
#define K_DIM 1024
#define E_NUM 8
#define DFF   2816
#define TOPK  2
#define NROWS (M_TOK*TOPK)   // 4096 routed rows
#define KSPLIT 4
#define KT2    (DFF / 64 / KSPLIT)   // 11

typedef __bf16 bf16;
typedef __bf16 bf16x8 __attribute__((ext_vector_type(8)));
typedef __bf16 bf16x4 __attribute__((ext_vector_type(4)));
typedef float  f32x4  __attribute__((ext_vector_type(4)));

__device__ __forceinline__ void gload_lds16(const void* g, void* l) {
    __builtin_amdgcn_global_load_lds(
        (const __attribute__((address_space(1))) void*)g,
        (__attribute__((address_space(3))) void*)l, 16, 0, 0);
}

// ---------------------------------------------------------------------------
// Zero d_out (grid-stride f32x4).
// ---------------------------------------------------------------------------
__global__ __launch_bounds__(256)
void zero_kernel(float* __restrict__ p, int n4)
{
    int i = blockIdx.x * 256 + threadIdx.x;
    int stride = gridDim.x * 256;
    f32x4 z = (f32x4){0.f, 0.f, 0.f, 0.f};
    for (; i < n4; i += stride) ((f32x4*)p)[i] = z;
}

// ---------------------------------------------------------------------------
// Routing (unchanged, verified).
// ---------------------------------------------------------------------------
__global__ __launch_bounds__(512)
void route_kernel(const int* __restrict__ ids,
                  const float* __restrict__ tw,
                  int* __restrict__ counts, int* __restrict__ offs,
                  int* __restrict__ row_token, float* __restrict__ row_wgt)
{
    const int e    = threadIdx.x >> 6;
    const int lane = threadIdx.x & 63;
    __shared__ int scnt[E_NUM];

    int cnt = 0;
    for (int i0 = 0; i0 < NROWS; i0 += 64) {
        int id = ids[i0 + lane];
        cnt += __popcll(__ballot(id == e));
    }
    if (lane == 0) scnt[e] = cnt;
    __syncthreads();
    int base = 0;
    for (int j = 0; j < e; ++j) base += scnt[j];
    if (lane == 0) { counts[e] = cnt; offs[e] = base; }

    const unsigned long long ltmask = (1ull << lane) - 1ull;
    int pos = base;
    for (int i0 = 0; i0 < NROWS; i0 += 64) {
        int i = i0 + lane;
        int id = ids[i];
        unsigned long long m = __ballot(id == e);
        if (id == e) {
            int rank = __popcll(m & ltmask);
            row_token[pos + rank] = i >> 1;
            row_wgt[pos + rank]   = tw[i];
        }
        pos += __popcll(m);
    }
}

// ---------------------------------------------------------------------------
// Gather routed rows of X and cast to bf16 (A operand only; 8 MB, ~4us).
// ---------------------------------------------------------------------------
__global__ __launch_bounds__(256)
void gather_cast_kernel(const float* __restrict__ X, const int* __restrict__ row_token,
                        bf16* __restrict__ Ag)
{
    const int row = blockIdx.x;
    const int tok = row_token[row];
    f32x4 a = ((const f32x4*)(X + (size_t)tok * K_DIM))[threadIdx.x];
    bf16x4 v;
    #pragma unroll
    for (int j = 0; j < 4; ++j) v[j] = (bf16)a[j];
    ((bf16x4*)(Ag + (size_t)row * K_DIM))[threadIdx.x] = v;
}

// ---------------------------------------------------------------------------
// GEMM1 + silu_and_mul. A = Ag (bf16) staged as before; B = w1 RAW f32 staged
// via gload_lds into a 32KB f32 LDS tile, converted to bf16 on the LDS->reg
// read (fuses the former cast2 pass; weight HBM traffic drops ~2x).
// B LDS law: content(row, c) = global f32x4-chunk c ^ (row & 15); dest linear
// (slot = q*256 + t == wave base + lane*16, rule 21); source pre-swizzled.
// ---------------------------------------------------------------------------
__global__ __launch_bounds__(256, 2)
void gemm1_kernel(const bf16* __restrict__ Ag, const float* __restrict__ w1,
                  const int* __restrict__ counts, const int* __restrict__ offs,
                  bf16* __restrict__ act)
{
    const int e  = blockIdx.z;
    const int rt = blockIdx.y;
    const int ct = blockIdx.x;              // 0..43
    const int n  = counts[e];
    const int r0 = rt * 128;
    if (r0 >= n) return;
    const int base = offs[e];

    __shared__ __align__(16) bf16  As[128*64];   // 16 KB
    __shared__ __align__(16) float Bs[128*64];   // 32 KB (f32!)
    bf16x8* Asv = (bf16x8*)As;
    f32x4*  BsF = (f32x4*)Bs;               // [row][16 chunks]

    const int t    = threadIdx.x;
    const int lane = t & 63, wv = t >> 6;

    // A staging (bf16, law c^(r&7), verified rounds 8-11)
    const int rlowA = lane >> 3;
    const int cgA   = (lane & 7) ^ rlowA;
    const bf16* aPtr[4]; bf16* aLds[4];
    #pragma unroll
    for (int i = 0; i < 4; ++i) {
        int r = wv*32 + i*8 + rlowA;
        aPtr[i] = Ag + (size_t)(base + r0 + r) * K_DIM + cgA*8;
        aLds[i] = As + (wv*32 + i*8)*64;
    }

    // B staging (f32): thread t -> slot q*256+t; row=q*16+(t>>4), c=t&15.
    const int rB  = t >> 4;                 // 0..15
    const int cgB = (t & 15) ^ rB;          // source chunk (pre-swizzled)
    const float* bGate = w1 + ((size_t)e*(2*DFF) + ct*64 + rB) * K_DIM + cgB*4;
    const float* bUp   = w1 + ((size_t)e*(2*DFF) + DFF + ct*64 + rB) * K_DIM + cgB*4;
    float* bLdsW = Bs + wv*256;             // wave-uniform LDS base (floats)

    const int wr = wv >> 1, wc = wv & 1;
    const int l15 = lane & 15, lq = lane >> 4;

    f32x4 accG[4][2], accU[4][2];
    #pragma unroll
    for (int m = 0; m < 4; ++m)
        #pragma unroll
        for (int nn = 0; nn < 2; ++nn) {
            accG[m][nn] = (f32x4){0.f,0.f,0.f,0.f};
            accU[m][nn] = (f32x4){0.f,0.f,0.f,0.f};
        }

#define G1_STAGE(KT_) do { \
    _Pragma("unroll") for (int i = 0; i < 4; ++i) \
        gload_lds16(aPtr[i] + (KT_)*64, aLds[i]); \
    _Pragma("unroll") for (int q = 0; q < 4; ++q) { \
        gload_lds16(bGate + (size_t)q*16*K_DIM + (KT_)*64, bLdsW + q*1024); \
        gload_lds16(bUp   + (size_t)q*16*K_DIM + (KT_)*64, bLdsW + (q+4)*1024); \
    } } while (0)

#define G1_CVT8(DST_, ROW_) do { \
    f32x4 lo_ = BsF[(ROW_)*16 + (g0 ^ l15)]; \
    f32x4 hi_ = BsF[(ROW_)*16 + ((g0+1) ^ l15)]; \
    _Pragma("unroll") for (int j = 0; j < 4; ++j) { \
        DST_[j] = (bf16)lo_[j]; DST_[j+4] = (bf16)hi_[j]; } \
    } while (0)

#define G1_COMPUTE() do { \
    _Pragma("unroll") for (int ks = 0; ks < 2; ++ks) { \
        const int g0 = 8*ks + 2*lq; \
        bf16x8 af[4], bg[2], bu[2]; \
        _Pragma("unroll") for (int m = 0; m < 4; ++m) { \
            int fr = wr*64 + m*16 + l15; \
            af[m] = Asv[fr*8 + ((ks*4 + lq) ^ (fr & 7))]; \
        } \
        _Pragma("unroll") for (int nn = 0; nn < 2; ++nn) { \
            int frg = wc*32 + nn*16 + l15; \
            G1_CVT8(bg[nn], frg); \
            int fru = 64 + wc*32 + nn*16 + l15; \
            G1_CVT8(bu[nn], fru); \
        } \
        _Pragma("unroll") for (int m = 0; m < 4; ++m) \
            _Pragma("unroll") for (int nn = 0; nn < 2; ++nn) { \
                accG[m][nn] = __builtin_amdgcn_mfma_f32_16x16x32_bf16(af[m], bg[nn], accG[m][nn], 0, 0, 0); \
                accU[m][nn] = __builtin_amdgcn_mfma_f32_16x16x32_bf16(af[m], bu[nn], accU[m][nn], 0, 0, 0); \
            } \
    } } while (0)

    const int KT = K_DIM / 64;   // 16
    G1_STAGE(0);
    for (int kt = 0; kt < KT; ++kt) {
        __syncthreads();                    // drain vmcnt + barrier
        G1_COMPUTE();
        if (kt + 1 < KT) { __syncthreads(); G1_STAGE(kt + 1); }
    }

    // epilogue: act = silu(gate) * up  (C/D: col=lane&15, row=(lane>>4)*4+r)
    #pragma unroll
    for (int m = 0; m < 4; ++m)
        #pragma unroll
        for (int nn = 0; nn < 2; ++nn)
            #pragma unroll
            for (int r = 0; r < 4; ++r) {
                int rl = wr*64 + m*16 + lq*4 + r;
                int grow = r0 + rl;
                if (grow < n) {
                    float g = accG[m][nn][r];
                    float u = accU[m][nn][r];
                    float a = (g / (1.f + __expf(-g))) * u;
                    int col = ct*64 + wc*32 + nn*16 + l15;
                    act[(size_t)(base + grow) * DFF + col] = (bf16)a;
                }
            }
#undef G1_STAGE
#undef G1_CVT8
#undef G1_COMPUTE
}

// ---------------------------------------------------------------------------
// GEMM2: A = act (bf16) as before; B = w2 RAW f32 via the same staged-f32
// scheme. KSPLIT=4 over DFF; atomic scatter epilogue.
// ---------------------------------------------------------------------------
__global__ __launch_bounds__(256, 2)
void gemm2_kernel(const bf16* __restrict__ act, const float* __restrict__ w2,
                  const int* __restrict__ counts, const int* __restrict__ offs,
                  const int* __restrict__ row_token, const float* __restrict__ row_wgt,
                  float* __restrict__ out)
{
    const int e   = blockIdx.z;
    const int rt  = blockIdx.y;
    const int ct  = blockIdx.x >> 2;          // 0..7 : 128 out cols
    const int ksp = blockIdx.x & 3;           // DFF quarter
    const int n   = counts[e];
    const int r0  = rt * 128;
    if (r0 >= n) return;
    const int base = offs[e];

    __shared__ __align__(16) bf16  As[128*64];   // 16 KB
    __shared__ __align__(16) float Bs[128*64];   // 32 KB
    bf16x8* Asv = (bf16x8*)As;
    f32x4*  BsF = (f32x4*)Bs;

    const int t    = threadIdx.x;
    const int lane = t & 63, wv = t >> 6;

    const int rlowA = lane >> 3;
    const int cgA   = (lane & 7) ^ rlowA;
    const bf16* aPtr[4]; bf16* aLds[4];
    #pragma unroll
    for (int i = 0; i < 4; ++i) {
        int r = wv*32 + i*8 + rlowA;
        aPtr[i] = act + (size_t)(base + r0 + r) * DFF + ksp*(DFF/KSPLIT) + cgA*8;
        aLds[i] = As + (wv*32 + i*8)*64;
    }

    const int rB  = t >> 4;
    const int cgB = (t & 15) ^ rB;
    const float* bBase = w2 + ((size_t)e*K_DIM + ct*128 + rB) * DFF + ksp*(DFF/KSPLIT) + cgB*4;
    float* bLdsW = Bs + wv*256;

    const int wr = wv >> 1, wc = wv & 1;
    const int l15 = lane & 15, lq = lane >> 4;

    f32x4 acc[4][4];
    #pragma unroll
    for (int m = 0; m < 4; ++m)
        #pragma unroll
        for (int nn = 0; nn < 4; ++nn) acc[m][nn] = (f32x4){0.f,0.f,0.f,0.f};

#define G2_STAGE(KT_) do { \
    _Pragma("unroll") for (int i = 0; i < 4; ++i) \
        gload_lds16(aPtr[i] + (KT_)*64, aLds[i]); \
    _Pragma("unroll") for (int q = 0; q < 8; ++q) \
        gload_lds16(bBase + (size_t)q*16*DFF + (KT_)*64, bLdsW + q*1024); \
    } while (0)

#define G2_CVT8(DST_, ROW_) do { \
    f32x4 lo_ = BsF[(ROW_)*16 + (g0 ^ l15)]; \
    f32x4 hi_ = BsF[(ROW_)*16 + ((g0+1) ^ l15)]; \
    _Pragma("unroll") for (int j = 0; j < 4; ++j) { \
        DST_[j] = (bf16)lo_[j]; DST_[j+4] = (bf16)hi_[j]; } \
    } while (0)

#define G2_COMPUTE() do { \
    _Pragma("unroll") for (int ks = 0; ks < 2; ++ks) { \
        const int g0 = 8*ks + 2*lq; \
        bf16x8 af[4], bf[4]; \
        _Pragma("unroll") for (int m = 0; m < 4; ++m) { \
            int fr = wr*64 + m*16 + l15; \
            af[m] = Asv[fr*8 + ((ks*4 + lq) ^ (fr & 7))]; \
        } \
        _Pragma("unroll") for (int nn = 0; nn < 4; ++nn) { \
            int fr = wc*64 + nn*16 + l15; \
            G2_CVT8(bf[nn], fr); \
        } \
        _Pragma("unroll") for (int m = 0; m < 4; ++m) \
            _Pragma("unroll") for (int nn = 0; nn < 4; ++nn) \
                acc[m][nn] = __builtin_amdgcn_mfma_f32_16x16x32_bf16(af[m], bf[nn], acc[m][nn], 0, 0, 0); \
    } } while (0)

    G2_STAGE(0);
    for (int kt = 0; kt < KT2; ++kt) {
        __syncthreads();
        G2_COMPUTE();
        if (kt + 1 < KT2) { __syncthreads(); G2_STAGE(kt + 1); }
    }

    #pragma unroll
    for (int m = 0; m < 4; ++m)
        #pragma unroll
        for (int nn = 0; nn < 4; ++nn)
            #pragma unroll
            for (int r = 0; r < 4; ++r) {
                int rl = wr*64 + m*16 + lq*4 + r;
                int grow = r0 + rl;
                if (grow < n) {
                    int idx = base + grow;
                    int tok   = row_token[idx];
                    float wgt = row_wgt[idx];
                    int col = ct*128 + wc*64 + nn*16 + l15;
                    atomicAdd(out + (size_t)tok * K_DIM + col, wgt * acc[m][nn][r]);
                }
            }
#undef G2_STAGE
#undef G2_CVT8
#undef G2_COMPUTE
}

// ---------------------------------------------------------------------------
extern "C" void kernel_launch(void* const* d_in, const int* in_sizes, int n_in,
                              void* d_out, int out_size, void* d_ws, size_t ws_size,
                              hipStream_t stream)
{
    const float* X   = (const float*)d_in[0];
    const float* w1  = (const float*)d_in[1];
    const float* w2  = (const float*)d_in[2];
    const float* tw  = (const float*)d_in[3];
    const int*   ids = (const int*)d_in[4];
    float* out = (float*)d_out;

    // ws layout: act | row_token | row_wgt | counts | offs | Ag | pad
    // (pad absorbs the benign A-row overreads past the last expert's tile)
    char* p = (char*)d_ws;
    bf16*  act       = (bf16*)p;   p += (size_t)NROWS * DFF * 2;
    int*   row_token = (int*)p;    p += (size_t)NROWS * 4;
    float* row_wgt   = (float*)p;  p += (size_t)NROWS * 4;
    int*   counts    = (int*)p;    p += 32;
    int*   offs      = (int*)p;    p += 32;
    bf16*  Ag        = (bf16*)p;   p += (size_t)NROWS * K_DIM * 2;
    p += (1u << 20);               // 1 MB pad
    (void)p; (void)ws_size;        // NEEDED ~33 MB << ws (>=162 MB verified r8-11)

    zero_kernel<<<512, 256, 0, stream>>>(out, out_size / 4);
    route_kernel<<<1, 512, 0, stream>>>(ids, tw, counts, offs, row_token, row_wgt);
    gather_cast_kernel<<<NROWS, 256, 0, stream>>>(X, row_token, Ag);
    gemm1_kernel<<<dim3(DFF/64, NROWS/128, E_NUM), 256, 0, stream>>>(Ag, w1, counts, offs, act);
    gemm2_kernel<<<dim3((K_DIM/128)*KSPLIT, NROWS/128, E_NUM), 256, 0, stream>>>(act, w2, counts, offs, row_token, row_wgt, out);
}